// Round 9
// baseline (234.773 us; speedup 1.0000x reference)
//
#include <hip/hip_runtime.h>
#include <cstdint>

#define LRELU_ALPHA 0.2f
#define NEG_INF -9000000000000000.0f
#define L2E 1.4426950408889634f

typedef __bf16 bf16x8 __attribute__((ext_vector_type(8)));
typedef float floatx4 __attribute__((ext_vector_type(4)));
typedef unsigned int uintx4 __attribute__((ext_vector_type(4)));

constexpr int Bb = 8, Nn = 2048, Ff = 64;
constexpr int TJ = 64;             // j-tile width
constexpr int SEGW = 8;            // waves per block = in-block j-slices
constexpr int SLICE = Nn / SEGW;   // 256 j per wave
constexpr int NT = SLICE / TJ;     // 4 tiles per wave
constexpr int NROWS = Bb * Nn;     // 16384 global rows

__device__ __forceinline__ unsigned short f2bf(float f) {
    unsigned u = __builtin_bit_cast(unsigned, f);
    u = u + 0x7FFFu + ((u >> 16) & 1u);   // round-to-nearest-even
    return (unsigned short)(u >> 16);
}

__device__ __forceinline__ unsigned cvt_pk_bf16(float lo, float hi) {
    unsigned r;
    asm("v_cvt_pk_bf16_f32 %0, %1, %2" : "=v"(r) : "v"(lo), "v"(hi));
    return r;
}

// ---------------- Kernel 1: h = x@W (fp32), s1 = h.a1, s2 = h.a2, hT (bf16, transposed) ----
// grid 512, block 256 = 4 waves; wave w owns rows il = w*8 + r.
__global__ __launch_bounds__(256) void gat_prep(
    const float* __restrict__ x, const float* __restrict__ W, const float* __restrict__ a,
    unsigned short* __restrict__ hT, float* __restrict__ s1g, float* __restrict__ s2g)
{
    constexpr int STR2 = 36;                    // [f][il] stride (bank-stride 18 -> 2-way = free)
    __shared__ unsigned short hblk[64 * STR2];
    const int tid = threadIdx.x;
    const int blk = blockIdx.x;                 // 512 blocks: 64 row-blocks x 8 batches
    const int b  = blk >> 6;
    const int i0 = (blk & 63) * 32;
    const int w    = tid >> 6;
    const int lane = tid & 63;                  // lane = output feature f

    float wcol[64];
    #pragma unroll
    for (int k = 0; k < 64; ++k) wcol[k] = W[k * 64 + lane];
    const float a1 = a[lane], a2 = a[64 + lane];

    for (int r = 0; r < 8; ++r) {
        const int il = w * 8 + r;
        const int i  = i0 + il;
        const float* xrow = x + ((size_t)(b * Nn + i)) * 64;   // wave-uniform -> s_loads
        float h0 = 0.f, h1 = 0.f, h2 = 0.f, h3 = 0.f;
        #pragma unroll
        for (int k = 0; k < 64; k += 4) {
            h0 = fmaf(xrow[k],     wcol[k],     h0);
            h1 = fmaf(xrow[k + 1], wcol[k + 1], h1);
            h2 = fmaf(xrow[k + 2], wcol[k + 2], h2);
            h3 = fmaf(xrow[k + 3], wcol[k + 3], h3);
        }
        const float h = (h0 + h1) + (h2 + h3);
        float p1 = h * a1, p2 = h * a2;
        #pragma unroll
        for (int off = 32; off; off >>= 1) {
            p1 += __shfl_xor(p1, off);
            p2 += __shfl_xor(p2, off);
        }
        if (lane == 0) { s1g[b * Nn + i] = p1; s2g[b * Nn + i] = p2; }
        hblk[lane * STR2 + il] = f2bf(h);          // transpose via LDS
    }
    __syncthreads();
    {
        const int f = tid >> 2, c = (tid & 3) * 8;
        uint4 v = *reinterpret_cast<const uint4*>(&hblk[f * STR2 + c]);
        *reinterpret_cast<uint4*>(hT + ((size_t)b * 64 + f) * Nn + i0 + c) = v;
    }
}

// ---------------- Kernel 2: fused adj-pack + softmax-free attention (BARRIER-FREE waves) ---
// Block = 512 threads = 8 waves; block owns 16 rows; wave s sweeps j-slice [s*256,(s+1)*256).
// v9: NO block-wide barrier until the final merge. Each wave is fully self-sufficient:
//   - loads the WHOLE s2 batch row (8x float4, L2-hot) for its own batch-max reduce
//     (replaces the cross-wave smax_lds + __syncthreads of v8),
//   - stages only ITS OWN s2 slice into a wave-private LDS region (wave-local RAW),
//   - packs its own 16-row x 256-col adj window via batched int4 loads + ballots
//     (issued after the s2 loads; smax consumes s2 under a counted vmcnt with all
//     16 adj loads still in flight).
// Waves therefore desynchronize freely: some stream adj from HBM while others run
// exp/MFMA — memory never idles behind a phase barrier (v8's ~3x-over-floor stall).
// LDS deliberately >53.3 KB -> 2 blocks/CU; __launch_bounds__(512,4) -> 128-VGPR budget.
__global__ __launch_bounds__(512, 4) void gat_attn(
    const int* __restrict__ adj, const unsigned short* __restrict__ hT,
    const float* __restrict__ s1g, const float* __restrict__ s2g,
    float* __restrict__ out)
{
    __shared__ unsigned long long mk_lds[SEGW][16][6];  // [wave][row][4 words + 2 pad]
    __shared__ float s2_lds[Nn];                        // [wave s: s*256 .. s*256+255] private
    __shared__ float O_lds[SEGW][16][65];
    __shared__ float l_lds[SEGW][16];
    __shared__ float lds_pad[2048];                     // occupancy shaping -> 2 blocks/CU

    const int tid  = threadIdx.x;
    const int blk  = blockIdx.x;          // 1024 blocks: 128 per batch
    const int b    = blk >> 7;
    const int i0   = (blk & 127) * 16;
    const int s    = tid >> 6;            // wave id = j-slice
    const int lane = tid & 63;
    const int fl   = lane & 15;           // A-row (i) in e-phase; B-col (f) in mfma phase
    const int q    = lane >> 4;           // quad id: k-group selector

    const int i = i0 + fl;                // this lane's score row
    if (blk == 0x7FFFFFFF) lds_pad[tid] = (float)tid;   // keep pad alive (never true)

    // ---- issue s2 full-row loads first (8 x 1KB coalesced; smax + own slice) ----
    float4 sv[8];
    {
        const float* s2row = s2g + b * Nn;
        #pragma unroll
        for (int k = 0; k < 8; ++k)
            sv[k] = *reinterpret_cast<const float4*>(&s2row[k * 256 + lane * 4]);
    }

    // ---- issue the wave's 16 batched int4 adj loads (row i0+r, j = s*256 + 4*lane + c) ----
    const int4* adjb = reinterpret_cast<const int4*>(adj + (size_t)(b * Nn + i0) * Nn);
    int4 va[16];
    #pragma unroll
    for (int r = 0; r < 16; ++r)
        va[r] = adjb[(size_t)r * (Nn / 4) + s * 64 + lane];

    const float s1v = s1g[b * Nn + i];

    // ---- batch max of s2 (consumes sv under counted vmcnt; adj still in flight) ----
    float s2mx;
    {
        float sm = fmaxf(fmaxf(sv[0].x, sv[0].y), fmaxf(sv[0].z, sv[0].w));
        #pragma unroll
        for (int k = 1; k < 8; ++k)
            sm = fmaxf(sm, fmaxf(fmaxf(sv[k].x, sv[k].y), fmaxf(sv[k].z, sv[k].w)));
        #pragma unroll
        for (int off = 32; off; off >>= 1) sm = fmaxf(sm, __shfl_xor(sm, off));
        s2mx = sm;
    }
    // stage OWN slice into wave-private LDS region (k = s chunk of the row)
    *reinterpret_cast<float4*>(&s2_lds[s * SLICE + lane * 4]) = sv[s];

    float mub = s1v + s2mx;
    mub = fmaxf(mub, LRELU_ALPHA * mub);   // leaky(s1 + max s2) >= true row max (monotonic)
    const float ci = -mub * L2E;           // exp2 arg bias

    // ---- ballots: word k of row r: bit l <-> adj[i0+r][s*256 + 4*l + k] > 0 ----
    {
        unsigned long long acc = 0;
        #pragma unroll
        for (int r = 0; r < 16; ++r) {
            const unsigned long long m0 = __ballot(va[r].x > 0);
            const unsigned long long m1 = __ballot(va[r].y > 0);
            const unsigned long long m2 = __ballot(va[r].z > 0);
            const unsigned long long m3 = __ballot(va[r].w > 0);
            const unsigned long long sel = (lane & 2) ? ((lane & 1) ? m3 : m2)
                                                      : ((lane & 1) ? m1 : m0);
            if ((lane >> 2) == r) acc = sel;       // lane l holds (row l>>2, word l&3)
        }
        mk_lds[s][lane >> 2][lane & 3] = acc;      // wave-private region; compiler orders RAW
    }
    // lane's row-fl mask words for the whole slice (all 4 tiles): 4 u64 in regs
    const unsigned long long w0 = mk_lds[s][fl][0];
    const unsigned long long w1 = mk_lds[s][fl][1];
    const unsigned long long w2 = mk_lds[s][fl][2];
    const unsigned long long w3 = mk_lds[s][fl][3];

    const unsigned short* hTb = hT + (size_t)b * 64 * Nn + s * SLICE;
    const float* sl0 = &s2_lds[s * SLICE];

    // ---- Phase B: softmax-free attention over this wave's j-slice ----
    float l = 0.f;
    floatx4 C[4] = {};                    // 4 f-tiles of 16x16 C

    #pragma unroll
    for (int jt = 0; jt < NT; ++jt) {
        const int jloc = jt * TJ;

        bf16x8 Bv[8];
        #pragma unroll
        for (int u = 0; u < 4; ++u) {
            Bv[2 * u] = *reinterpret_cast<const bf16x8*>(
                hTb + (size_t)(u * 16 + fl) * Nn + jloc + q * 8);
            Bv[2 * u + 1] = *reinterpret_cast<const bf16x8*>(
                hTb + (size_t)(u * 16 + fl) * Nn + jloc + 32 + q * 8);
        }

        const float4 sA = *reinterpret_cast<const float4*>(&sl0[jloc + q * 8]);
        const float4 sB = *reinterpret_cast<const float4*>(&sl0[jloc + q * 8 + 4]);
        const float4 sC = *reinterpret_cast<const float4*>(&sl0[jloc + 32 + q * 8]);
        const float4 sD = *reinterpret_cast<const float4*>(&sl0[jloc + 32 + q * 8 + 4]);

        // mask bits: local off = jt*64 + tt*32 + q*8 + jj -> word jj&3, bit jt*16+tt*8+q*2+(jj>>2)
        const unsigned b0 = (unsigned)(jt * 16 + q * 2);
        const unsigned t0w0 = (unsigned)(w0 >> b0),       t0w1 = (unsigned)(w1 >> b0);
        const unsigned t0w2 = (unsigned)(w2 >> b0),       t0w3 = (unsigned)(w3 >> b0);
        const unsigned t1w0 = (unsigned)(w0 >> (b0 + 8)), t1w1 = (unsigned)(w1 >> (b0 + 8));
        const unsigned t1w2 = (unsigned)(w2 >> (b0 + 8)), t1w3 = (unsigned)(w3 >> (b0 + 8));

        float p[16];
        {
            const float s2v0[8] = { sA.x, sA.y, sA.z, sA.w, sB.x, sB.y, sB.z, sB.w };
            const float s2v1[8] = { sC.x, sC.y, sC.z, sC.w, sD.x, sD.y, sD.z, sD.w };
            const unsigned tw0[4] = { t0w0, t0w1, t0w2, t0w3 };
            const unsigned tw1[4] = { t1w0, t1w1, t1w2, t1w3 };
            #pragma unroll
            for (int jj = 0; jj < 8; ++jj) {
                float ev = s1v + s2v0[jj];
                ev = fmaxf(ev, LRELU_ALPHA * ev);              // leaky_relu, alpha<1
                const float t = exp2f(fmaf(ev, L2E, ci));
                p[jj] = ((tw0[jj & 3] >> (jj >> 2)) & 1u) ? t : 0.f;
                l += p[jj];
            }
            #pragma unroll
            for (int jj = 0; jj < 8; ++jj) {
                float ev = s1v + s2v1[jj];
                ev = fmaxf(ev, LRELU_ALPHA * ev);
                const float t = exp2f(fmaf(ev, L2E, ci));
                p[8 + jj] = ((tw1[jj & 3] >> (jj >> 2)) & 1u) ? t : 0.f;
                l += p[8 + jj];
            }
        }

        // pack p -> bf16 A-fragments
        uintx4 pa, pb;
        #pragma unroll
        for (int d = 0; d < 4; ++d) {
            pa[d] = cvt_pk_bf16(p[2 * d],     p[2 * d + 1]);
            pb[d] = cvt_pk_bf16(p[8 + 2 * d], p[8 + 2 * d + 1]);
        }
        const bf16x8 A0 = __builtin_bit_cast(bf16x8, pa);
        const bf16x8 A1 = __builtin_bit_cast(bf16x8, pb);

        // PV: 4 f-tiles x 2 k-steps
        __builtin_amdgcn_s_setprio(1);
        #pragma unroll
        for (int u = 0; u < 4; ++u) {
            C[u] = __builtin_amdgcn_mfma_f32_16x16x32_bf16(A0, Bv[2 * u],     C[u], 0, 0, 0);
            C[u] = __builtin_amdgcn_mfma_f32_16x16x32_bf16(A1, Bv[2 * u + 1], C[u], 0, 0, 0);
        }
        __builtin_amdgcn_s_setprio(0);
    }

    // one l-reduce per wave (cross-quad), not per tile
    l += __shfl_xor(l, 16);
    l += __shfl_xor(l, 32);

    // ---- in-block merge of the 8 j-slice partials (sum-only: all share m_ub) ----
    #pragma unroll
    for (int u = 0; u < 4; ++u)
        #pragma unroll
        for (int r = 0; r < 4; ++r)
            O_lds[s][q * 4 + r][u * 16 + fl] = C[u][r];
    if (q == 0) l_lds[s][fl] = l;
    __syncthreads();                       // the ONLY block-wide barrier

    // 1024 outputs, 512 threads -> 2 consecutive f each; coalesced float2 store
    const int row = tid >> 5;
    const int f0  = (tid & 31) * 2;

    float lsum = 0.f, acc0 = 0.f, acc1 = 0.f;
    #pragma unroll
    for (int k = 0; k < SEGW; ++k) {
        lsum += l_lds[k][row];
        const float2 ov = *reinterpret_cast<const float2*>(&O_lds[k][row][f0]);
        acc0 += ov.x;
        acc1 += ov.y;
    }
    const float inv = 1.f / lsum;
    float v0 = acc0 * inv, v1 = acc1 * inv;
    v0 = (v0 > 0.f) ? v0 : (exp2f(v0 * L2E) - 1.f);    // elu, alpha=1
    v1 = (v1 > 0.f) ? v1 : (exp2f(v1 * L2E) - 1.f);
    float2 o2; o2.x = v0; o2.y = v1;
    *reinterpret_cast<float2*>(&out[((size_t)(b * Nn + i0 + row)) * 64 + f0]) = o2;
}

extern "C" void kernel_launch(void* const* d_in, const int* in_sizes, int n_in,
                              void* d_out, int out_size, void* d_ws, size_t ws_size,
                              hipStream_t stream) {
    const float* x   = (const float*)d_in[0];
    const int*   adj = (const int*)d_in[1];
    const float* W   = (const float*)d_in[2];
    const float* a   = (const float*)d_in[3];
    float* out = (float*)d_out;

    // workspace: hT bf16 [B][64][N] (2 MB) + s1,s2 fp32 [B*N] (64 KB each)
    char* p = (char*)d_ws;
    unsigned short* hT = (unsigned short*)p;  p += (size_t)Bb * 64 * Nn * sizeof(unsigned short);
    float* s1 = (float*)p;                    p += (size_t)NROWS * sizeof(float);
    float* s2 = (float*)p;

    gat_prep<<<dim3(Bb * Nn / 32), dim3(256), 0, stream>>>(x, W, a, hT, s1, s2);
    gat_attn<<<dim3(NROWS / 16), dim3(512), 0, stream>>>(adj, hT, s1, s2, out);
}